// Round 17
// baseline (331.810 us; speedup 1.0000x reference)
//
// VQ layer (gumbel-softmax VQ) fused pipeline for MI355X (gfx950). Round 17.
//
//   K0  split_w : W_h, W_logits -> f16 hi/lo planes in ws (2 MB)
//   K1  gemm8   : hiddens = relu(X @ Wh^T + bh). SINGLE-BARRIER deep
//                 pipeline: 4 LDS buffers, stage depth 3 — the buffer being
//                 staged was last read two steps ago (fenced by that step's
//                 WAITL0 + barrier), so staging overlaps THIS step's MFMAs
//                 and the second barrier of the classic 2-phase loop is
//                 eliminated. Per step: 1 barrier + WAITV(0) (drains loads
//                 issued 1-2 steps ago => ~0 stall; also guarantees
//                 global_load_lds data lands before the consuming barrier)
//                 + 1 WAITL0. Producer-split A (f32 X -> f16 hi/lo in reg ->
//                 ds_write, 2-access/bank verified pattern).
//                 (R5-R16 lesson: every 2-barrier K1 variant = 175-190us at
//                 ~25% MfmaUtil regardless of A-feed/swizzle/tile; MFMA pipe
//                 floor is 51us; the barrier structure was the cap.)
//   K2  gemm4<1>: logits = hiddens @ Wl^T + bl -> d_out (f32). PURE GEMM.
//   K3  argmax  : z = logits + gumbel(u); codes = codebook[argmax z].
//
// f32-GEMM emulation: a = hi + lo*2^-12 (f16 split, lo scaled 2^12), 3 MFMAs:
// hi.hi -> acc_hh ; hi.lo + lo.hi -> acc_mx ; D = acc_hh + acc_mx*2^-12.
//
// gemm8 sync proof sketch: buf cycle 4, S(t) stages step t+3 into
// buf[(t+3)&3]; that buf was read as frags at step t-1, whose ds_reads are
// drained by end-of-(t-1) WAITL0 and all waves pass top(t)'s barrier before
// S(t) writes -> no read/write race. B(t)'s gload_lds are drained by
// S(t-1)'s WAITV(0) (vmcnt in-order), which precedes top(t)'s barrier ->
// LDS-bypass data visible. A-reg deps (areg, frags) are compiler-guarded
// by auto-waitcnt; manual waits only shape overlap.

#include <hip/hip_runtime.h>
#include <hip/hip_fp16.h>

typedef _Float16 h16;
typedef __attribute__((ext_vector_type(8))) _Float16 h16x8;
typedef __attribute__((ext_vector_type(4))) _Float16 h16x4;
typedef __attribute__((ext_vector_type(4))) float f32x4;

#define KDIM 512
#define NDIM 512
#define LO_SCALE 4096.0f
#define LO_INV   0.000244140625f

__device__ __forceinline__ void gload16(const void* g, void* l) {
  __builtin_amdgcn_global_load_lds((const __attribute__((address_space(1))) void*)g,
                                   (__attribute__((address_space(3))) void*)l, 16, 0, 0);
}

#define WAITV(n) asm volatile("s_waitcnt vmcnt(" #n ")" ::: "memory")
#define WAITL0() asm volatile("s_waitcnt lgkmcnt(0)" ::: "memory")
#define SB() __builtin_amdgcn_sched_barrier(0)

// ---------------- K0: split weights into f16 hi/lo planes ----------------
__global__ void split_w(const float* __restrict__ Wh, const float* __restrict__ Wl,
                        h16* __restrict__ WhHi, h16* __restrict__ WhLo,
                        h16* __restrict__ WlHi, h16* __restrict__ WlLo) {
  int i = blockIdx.x * 256 + threadIdx.x;          // 262144 elements
  float a = Wh[i];
  h16 h = (h16)a;
  WhHi[i] = h; WhLo[i] = (h16)((a - (float)h) * LO_SCALE);
  a = Wl[i];
  h = (h16)a;
  WlHi[i] = h; WlLo[i] = (h16)((a - (float)h) * LO_SCALE);
}

// ====== K1: gemm8 — H = relu(X @ Wh^T + bh), single-barrier 4-buf ======
// Block 128M x 128N, 8 waves (wave tile 64x32: wm=wave>>2 in {0,1},
// wn=wave&3 in {0..3}), BK=32, 16 K-steps. LDS: 4 bufs x 32KB
// {A [128 rows][hi64|lo64] swA | B [128 rows][hi64|lo64] swB}.
__launch_bounds__(512, 2)
__global__ void gemm8_k(const float* __restrict__ X,
                        const h16* __restrict__ BHi, const h16* __restrict__ BLo,
                        const float* __restrict__ bias,
                        h16* __restrict__ OHi, h16* __restrict__ OLo) {
  __shared__ __align__(16) char lds[131072];
  const int tid = threadIdx.x;
  const int wave = tid >> 6, lane = tid & 63;
  const int wm = wave >> 2, wn = wave & 3;
  const int wg = (blockIdx.x & 7) * 256 + (blockIdx.x >> 3);  // XCD-chunked
  const int bm = wg >> 2, bn = wg & 3;             // 512 M-tiles x 4 N-tiles
  const long arow0 = (long)bm * 128;
  const int brow0 = bn * 128;
  const int q = lane >> 4, rlo = lane & 15;

  f32x4 acc_hh[4][2] = {};
  f32x4 acc_mx[4][2] = {};
  f32x4 areg[2][2];                                // 2 in-flight A k-steps

  const int axrow = tid >> 2;                      // X-tile row (0..127)
  const int akb = (tid & 3) * 32;                  // 32B chunk in 128B k-row
  const int ajb = (tid & 3) * 16;                  // 16B pos in 64B plane half
  const int asw = ((axrow & 1) << 6) | (((axrow >> 1) & 3) << 4);

  auto aload = [&](f32x4 (&ar)[2], int kt) {       // 16KB tile: 2 f32x4/thr
    const char* base = (const char*)X + (arow0 + axrow) * 2048 + (long)kt * 128 + akb;
    ar[0] = *(const f32x4*)base;
    ar[1] = *(const f32x4*)(base + 16);
  };
  auto awrite = [&](const f32x4 (&ar)[2], char* buf) {  // split + 2x ds_write_b128
    h16x8 hv, lv;
#pragma unroll
    for (int p = 0; p < 2; ++p)
#pragma unroll
      for (int e = 0; e < 4; ++e) {
        float a = ar[p][e];
        h16 h = (h16)a;
        hv[p * 4 + e] = h;
        lv[p * 4 + e] = (h16)((a - (float)h) * LO_SCALE);
      }
    *(h16x8*)(buf + axrow * 128 + (ajb ^ asw)) = hv;
    *(h16x8*)(buf + axrow * 128 + ((ajb + 64) ^ asw)) = lv;
  };
  auto bgld = [&](char* buf, int kt) {             // 16KB: 2 gload16/thread
#pragma unroll
    for (int pass = 0; pass < 2; ++pass) {
      int p = pass * 8192 + tid * 16;
      int row = p >> 7;                            // 0..127
      int gs = ((p >> 4) & 7) ^ (row & 7);
      const char* sp = (gs & 4) ? (const char*)BLo : (const char*)BHi;
      long off = (long)(brow0 + row) * 1024 + (long)kt * 64 + (gs & 3) * 16;
      gload16(sp + off, buf + 16384 + pass * 8192 + (tid >> 6) * 1024 +
                        (tid & 63) * 0);           // dest linear: base+lane*16
    }
  };
  // NOTE on bgld dest: global_load_lds dest is wave-uniform base + lane*16.
  // pass*8192 spans 512thr*16B; per wave the base is pass*8192 + wave*1024.

  auto bgld2 = [&](char* buf, int kt) {
#pragma unroll
    for (int pass = 0; pass < 2; ++pass) {
      int p = pass * 8192 + wave * 1024 + lane * 16;
      int row = p >> 7;
      int gs = ((p >> 4) & 7) ^ (row & 7);
      const char* sp = (gs & 4) ? (const char*)BLo : (const char*)BHi;
      long off = (long)(brow0 + row) * 1024 + (long)kt * 64 + (gs & 3) * 16;
      gload16(sp + off, buf + 16384 + pass * 8192 + wave * 1024);
    }
  };

  // ---- prologue: stage bufs 0,1,2 (steps 0,1,2); preload A3,A4 ----
  aload(areg[0], 0);
  aload(areg[1], 1);
  WAITV(2);                                        // A0 landed
  awrite(areg[0], lds);
  bgld2(lds, 0);
  aload(areg[0], 2);
  WAITV(2);                                        // A1 landed (keep A2)
  awrite(areg[1], lds + 32768);
  bgld2(lds + 32768, 1);
  aload(areg[1], 3);
  WAITV(2);                                        // A2 landed (keep A3)
  awrite(areg[0], lds + 65536);
  bgld2(lds + 65536, 2);
  aload(areg[0], 4);
  WAITL0();                                        // ds_writes drained
  SB();

#pragma unroll
  for (int t = 0; t < 16; ++t) {
    __builtin_amdgcn_s_barrier();                  // buf[t&3] fully staged
    SB();

    char* buf = lds + (t & 3) * 32768;
    h16x8 ah[4], al[4], bh[2], bl[2];
#pragma unroll
    for (int i = 0; i < 4; ++i) {
      int row = wm * 64 + i * 16 + rlo;
      int swa = ((row & 1) << 6) | (((row >> 1) & 3) << 4);
      ah[i] = *(const h16x8*)(buf + row * 128 + ((q * 16) ^ swa));
      al[i] = *(const h16x8*)(buf + row * 128 + ((q * 16 + 64) ^ swa));
    }
#pragma unroll
    for (int j = 0; j < 2; ++j) {
      int rb = wn * 32 + j * 16 + rlo;
      int swb = (rb & 7) << 4;
      bh[j] = *(const h16x8*)(buf + 16384 + rb * 128 + ((q * 16) ^ swb));
      bl[j] = *(const h16x8*)(buf + 16384 + rb * 128 + ((q * 16 + 64) ^ swb));
    }

    // first MFMA half (hh block)
    __builtin_amdgcn_s_setprio(1);
#pragma unroll
    for (int i = 0; i < 4; ++i)
#pragma unroll
      for (int j = 0; j < 2; ++j)
        acc_hh[i][j] = __builtin_amdgcn_mfma_f32_16x16x32_f16(ah[i], bh[j], acc_hh[i][j], 0, 0, 0);
    __builtin_amdgcn_s_setprio(0);

    // ---- stage zone (overlaps MFMAs; no extra barrier needed) ----
    if (t <= 12) {
      WAITV(0);                                    // A(t+3) + all B landed
      awrite(areg[(t + 3) & 1], lds + ((t + 3) & 3) * 32768);
      bgld2(lds + ((t + 3) & 3) * 32768, t + 3);
      if (t <= 11) aload(areg[(t + 4) & 1], t + 4);
    }

    // second MFMA half (cross terms)
    __builtin_amdgcn_s_setprio(1);
#pragma unroll
    for (int i = 0; i < 4; ++i)
#pragma unroll
      for (int j = 0; j < 2; ++j)
        acc_mx[i][j] = __builtin_amdgcn_mfma_f32_16x16x32_f16(ah[i], bl[j], acc_mx[i][j], 0, 0, 0);
#pragma unroll
    for (int i = 0; i < 4; ++i)
#pragma unroll
      for (int j = 0; j < 2; ++j)
        acc_mx[i][j] = __builtin_amdgcn_mfma_f32_16x16x32_f16(al[i], bh[j], acc_mx[i][j], 0, 0, 0);
    __builtin_amdgcn_s_setprio(0);

    WAITL0();                                      // frag reads + ds_writes done
    SB();
  }

  // ---- epilogue: relu+split -> u32 pack in LDS [128][128], coalesced ----
  __builtin_amdgcn_s_barrier();                    // all compute done; LDS free
#pragma unroll
  for (int j = 0; j < 2; ++j) {
    int lcol = wn * 32 + j * 16 + rlo;
    float bv = bias[bn * 128 + lcol];
#pragma unroll
    for (int i = 0; i < 4; ++i)
#pragma unroll
      for (int r = 0; r < 4; ++r) {
        int lrow = wm * 64 + i * 16 + q * 4 + r;
        float v = fmaxf(acc_hh[i][j][r] + acc_mx[i][j][r] * LO_INV + bv, 0.0f);
        h16 h = (h16)v;
        h16 l = (h16)((v - (float)h) * LO_SCALE);
        unsigned uu = (unsigned)__builtin_bit_cast(unsigned short, h) |
                      ((unsigned)__builtin_bit_cast(unsigned short, l) << 16);
        *(unsigned*)(lds + lrow * 512 + lcol * 4) = uu;
      }
  }
  __syncthreads();
#pragma unroll
  for (int pass = 0; pass < 8; ++pass) {
    int o = pass * 8192 + tid * 16;
    int lrow = o >> 9;                             // 512-B packed rows
    int lcb = o & 511;
    uint4 d = *(const uint4*)(lds + o);
    uint2 hi, lo;
    hi.x = (d.x & 0xffffu) | (d.y << 16);
    hi.y = (d.z & 0xffffu) | (d.w << 16);
    lo.x = (d.x >> 16) | (d.y & 0xffff0000u);
    lo.y = (d.z >> 16) | (d.w & 0xffff0000u);
    long gb = (arow0 + lrow) * 1024 + bn * 256 + (lcb >> 1);
    *(uint2*)((char*)OHi + gb) = hi;
    *(uint2*)((char*)OLo + gb) = lo;
  }
}

// ====== K2: gemm4 (presplit planes) — logits, pure GEMM (proven) ======
template <int EPI>
__launch_bounds__(256, 2)
__global__ void gemm4_k(const h16* __restrict__ AHi, const h16* __restrict__ ALo,
                        const h16* __restrict__ BHi, const h16* __restrict__ BLo,
                        const float* __restrict__ bias,
                        float* __restrict__ Cf32,
                        h16* __restrict__ OHi, h16* __restrict__ OLo) {
  __shared__ __align__(16) char lds[65536];
  const int tid = threadIdx.x;
  const int wave = tid >> 6, lane = tid & 63;
  const int wg = (blockIdx.x & 7) * 256 + (blockIdx.x >> 3);
  const int bm = wg >> 2, bn = wg & 3;
  const int wm = wave >> 1, wn = wave & 1;
  const long arow0 = (long)bm * 128;
  const int brow0 = bn * 128;
  const int q = lane >> 4, rlo = lane & 15;

  f32x4 acc_hh[4][4] = {};
  f32x4 acc_mx[4][4] = {};

#define STAGE4(bufoff, kt)                                                    \
  {                                                                           \
    _Pragma("unroll")                                                         \
    for (int pass = 0; pass < 4; ++pass) {                                    \
      int p = pass * 4096 + wave * 1024 + lane * 16;                          \
      int row = p >> 7;                                                       \
      int gs = ((p >> 4) & 7) ^ (row & 7);                                    \
      const char* sp = (gs & 4) ? (const char*)ALo : (const char*)AHi;        \
      long off = (arow0 + row) * 1024 + (kt) * 64 + (gs & 3) * 16;            \
      gload16(sp + off, lds + (bufoff) + pass * 4096 + wave * 1024);          \
    }                                                                         \
    _Pragma("unroll")                                                         \
    for (int pass = 0; pass < 4; ++pass) {                                    \
      int p = pass * 4096 + wave * 1024 + lane * 16;                          \
      int row = p >> 7;                                                       \
      int gs = ((p >> 4) & 7) ^ (row & 7);                                    \
      const char* sp = (gs & 4) ? (const char*)BLo : (const char*)BHi;        \
      long off = (long)(brow0 + row) * 1024 + (kt) * 64 + (gs & 3) * 16;      \
      gload16(sp + off, lds + (bufoff) + 16384 + pass * 4096 + wave * 1024);  \
    }                                                                         \
  }

  STAGE4(0, 0);
  STAGE4(32768, 1);

#pragma unroll
  for (int t = 0; t < 16; ++t) {
    if (t < 15) { WAITV(8); } else { WAITV(0); }
    SB();
    __builtin_amdgcn_s_barrier();
    SB();

    const char* buf = lds + (t & 1) * 32768;
    h16x8 ah[4], al[4], bh[4], bl[4];
#pragma unroll
    for (int i = 0; i < 4; ++i) {
      int row = wm * 64 + i * 16 + rlo;
      int sw = (row & 7) << 4;
      ah[i] = *(const h16x8*)(buf + row * 128 + ((q * 16) ^ sw));
      al[i] = *(const h16x8*)(buf + row * 128 + ((q * 16 + 64) ^ sw));
      int rb = wn * 64 + i * 16 + rlo;
      int swb = (rb & 7) << 4;
      bh[i] = *(const h16x8*)(buf + 16384 + rb * 128 + ((q * 16) ^ swb));
      bl[i] = *(const h16x8*)(buf + 16384 + rb * 128 + ((q * 16 + 64) ^ swb));
    }
#pragma unroll
    for (int i = 0; i < 4; ++i)
#pragma unroll
      for (int j = 0; j < 4; ++j)
        acc_hh[i][j] = __builtin_amdgcn_mfma_f32_16x16x32_f16(ah[i], bh[j], acc_hh[i][j], 0, 0, 0);
#pragma unroll
    for (int i = 0; i < 4; ++i)
#pragma unroll
      for (int j = 0; j < 4; ++j)
        acc_mx[i][j] = __builtin_amdgcn_mfma_f32_16x16x32_f16(ah[i], bl[j], acc_mx[i][j], 0, 0, 0);
#pragma unroll
    for (int i = 0; i < 4; ++i)
#pragma unroll
      for (int j = 0; j < 4; ++j)
        acc_mx[i][j] = __builtin_amdgcn_mfma_f32_16x16x32_f16(al[i], bh[j], acc_mx[i][j], 0, 0, 0);

    WAITL0();
    SB();
    __builtin_amdgcn_s_barrier();
    SB();
    if (t + 2 < 16) STAGE4((t & 1) * 32768, t + 2);
  }
#undef STAGE4

#pragma unroll
  for (int j = 0; j < 4; ++j) {
    int lcol = wn * 64 + j * 16 + rlo;
    float bv = bias[bn * 128 + lcol];
#pragma unroll
    for (int i = 0; i < 4; ++i)
#pragma unroll
      for (int r = 0; r < 4; ++r) {
        int lrow = wm * 64 + i * 16 + q * 4 + r;
        float v = acc_hh[i][j][r] + acc_mx[i][j][r] * LO_INV + bv;
        if (EPI == 0) {
          v = fmaxf(v, 0.0f);
          h16 h = (h16)v;
          h16 l = (h16)((v - (float)h) * LO_SCALE);
          unsigned uu = (unsigned)__builtin_bit_cast(unsigned short, h) |
                        ((unsigned)__builtin_bit_cast(unsigned short, l) << 16);
          *(unsigned*)(lds + lrow * 512 + lcol * 4) = uu;
        } else {
          *(float*)(lds + lrow * 512 + lcol * 4) = v;
        }
      }
  }
  __syncthreads();
#pragma unroll
  for (int pass = 0; pass < 16; ++pass) {
    int o = pass * 4096 + tid * 16;
    int lrow = o >> 9;
    int lcb = o & 511;
    if (EPI == 0) {
      uint4 d = *(const uint4*)(lds + o);
      uint2 hi, lo;
      hi.x = (d.x & 0xffffu) | (d.y << 16);
      hi.y = (d.z & 0xffffu) | (d.w << 16);
      lo.x = (d.x >> 16) | (d.y & 0xffff0000u);
      lo.y = (d.z >> 16) | (d.w & 0xffff0000u);
      long gb = (arow0 + lrow) * 1024 + bn * 256 + (lcb >> 1);
      *(uint2*)((char*)OHi + gb) = hi;
      *(uint2*)((char*)OLo + gb) = lo;
    } else {
      f32x4 d = *(const f32x4*)(lds + o);
      long gb = (arow0 + lrow) * 2048 + bn * 512 + lcb;
      *(f32x4*)((char*)Cf32 + gb) = d;
    }
  }
}

// ---------------- K3: gumbel + argmax + codebook gather ----------------
__global__ void k3_argmax_gather(const float* __restrict__ logits,
                                 const float* __restrict__ u,
                                 const float* __restrict__ cb,
                                 const int* __restrict__ testing,
                                 float* __restrict__ codes) {
  const int wave = threadIdx.x >> 6, lane = threadIdx.x & 63;
  const long row = (long)blockIdx.x * 4 + wave;    // one wave per row
  const f32x4* lrow = (const f32x4*)(logits + row * 512);
  const f32x4* urow = (const f32x4*)(u + row * 512);
  const int test = *testing;

  float best = -3.4e38f;
  int bi = 0;
#pragma unroll
  for (int h = 0; h < 2; ++h) {
    int c4 = h * 64 + lane;
    f32x4 z = lrow[c4];
    if (!test) {
      f32x4 uu = urow[c4];
#pragma unroll
      for (int t = 0; t < 4; ++t)
        z[t] += -logf(-logf(uu[t] + 1e-20f) + 1e-20f);
    }
#pragma unroll
    for (int t = 0; t < 4; ++t) {                  // in-lane ascending indices
      int c = c4 * 4 + t;
      if (z[t] > best) { best = z[t]; bi = c; }
    }
  }
#pragma unroll
  for (int off = 32; off; off >>= 1) {             // max with min-index ties
    float ob = __shfl_xor(best, off);
    int oi = __shfl_xor(bi, off);
    if (ob > best || (ob == best && oi < bi)) { best = ob; bi = oi; }
  }
  const f32x4* src = (const f32x4*)(cb + (long)bi * 512);
  f32x4* dst = (f32x4*)(codes + row * 512);
  dst[lane] = src[lane];
  dst[lane + 64] = src[lane + 64];
}

// ---------------- host ----------------
extern "C" void kernel_launch(void* const* d_in, const int* in_sizes, int n_in,
                              void* d_out, int out_size, void* d_ws, size_t ws_size,
                              hipStream_t stream) {
  const float* X = (const float*)d_in[0];
  const float* Wh = (const float*)d_in[1];
  const float* bh = (const float*)d_in[2];
  const float* Wl = (const float*)d_in[3];
  const float* bl = (const float*)d_in[4];
  const float* cb = (const float*)d_in[5];
  const float* u = (const float*)d_in[6];
  const int* testing = (const int*)d_in[7];

  float* logits = (float*)d_out;                   // 33554432 f32
  float* codes = logits + 33554432;                // 33554432 f32
  // hiddens hi/lo f16 planes live in the codes region until K3 overwrites it
  h16* Hhi = (h16*)codes;
  h16* Hlo = Hhi + 33554432;

  h16* WhHi = (h16*)d_ws;                          // 4 x 0.5 MB weight planes
  h16* WhLo = WhHi + 262144;
  h16* WlHi = WhLo + 262144;
  h16* WlLo = WlHi + 262144;

  split_w<<<dim3(1024), dim3(256), 0, stream>>>(Wh, Wl, WhHi, WhLo, WlHi, WlLo);

  gemm8_k<<<dim3(2048), dim3(512), 0, stream>>>(X, WhHi, WhLo, bh, Hhi, Hlo);

  gemm4_k<1><<<dim3(2048), dim3(256), 0, stream>>>(Hhi, Hlo, WlHi, WlLo, bl,
                                                   logits, nullptr, nullptr);

  k3_argmax_gather<<<dim3(16384), dim3(256), 0, stream>>>(logits, u, cb, testing, codes);
}

// Round 18
// 316.794 us; speedup vs baseline: 1.0474x; 1.0474x over previous
//
// VQ layer (gumbel-softmax VQ) fused pipeline for MI355X (gfx950). Round 18.
//
//   K0  split_w : W_h, W_logits -> f16 hi/lo planes in ws (2 MB)
//   K1  gemm9<1,0>: hiddens = relu(X @ Wh^T + bh); producer-split X.
//   K2  gemm9<0,1>: logits = hiddens @ Wl^T + bl; presplit H-planes.
//   K3  argmax  : z = logits + gumbel(u); codes = codebook[argmax z].
//
// R17 analysis: true MFMA floor = 12.4us/GEMM; all K1 variants ran 175-200us
// = 7% true util. Not HBM-bound (0.46-3 TB/s), not VALU, not conflicts (~5%).
// Limiter: per-CU staging throughput vs tile arithmetic intensity
// (MACs/staged-byte: 13-16 across R2-R17). Fix: 256Mx128N tile = 22 MACs/B,
// staged KB/CU/step halved. 8 waves x 64x64 (proven acc), BK=32, counted
// vmcnt 2-barrier (equal-best measured structure, fully understood).
//
// f32-GEMM emulation: a = hi + lo*2^-12 (f16 split, lo scaled 2^12), 3 MFMAs:
// hi.hi -> acc_hh ; hi.lo + lo.hi -> acc_mx ; D = acc_hh + acc_mx*2^-12.
//
// gemm9 K1 vmcnt ledger (aload=4, bgld=2): top-of-t queue {B(t)2, A(t+2)4,
// B(t+1)2} = 8 -> WAITV(6) drains B(t). Compute-start issues aload(t+3) -> 
// stage queue {A(t+2)4, B(t+1)2, A(t+3)4} = 10 -> WAITV(6) drains A(t+2);
// awrite; bgld(t+2) -> 8. Tails: t=13 stage WAITV(2) drains A15; t=14 top
// WAITV(2) drains B14; t=15 top WAITV(0) drains B15.
// K2 ledger (stage=6): {S(t)6, S(t+1)6} = 12 -> top WAITV(6) (t<=14), t=15
// WAITV(0); stage(t+2) after mid barrier for t<=13.

#include <hip/hip_runtime.h>
#include <hip/hip_fp16.h>

typedef _Float16 h16;
typedef __attribute__((ext_vector_type(8))) _Float16 h16x8;
typedef __attribute__((ext_vector_type(4))) float f32x4;

#define KDIM 512
#define NDIM 512
#define LO_SCALE 4096.0f
#define LO_INV   0.000244140625f

__device__ __forceinline__ void gload16(const void* g, void* l) {
  __builtin_amdgcn_global_load_lds((const __attribute__((address_space(1))) void*)g,
                                   (__attribute__((address_space(3))) void*)l, 16, 0, 0);
}

#define WAITV(n) asm volatile("s_waitcnt vmcnt(" #n ")" ::: "memory")
#define WAITL0() asm volatile("s_waitcnt lgkmcnt(0)" ::: "memory")
#define SB() __builtin_amdgcn_sched_barrier(0)

// ---------------- K0: split weights into f16 hi/lo planes ----------------
__global__ void split_w(const float* __restrict__ Wh, const float* __restrict__ Wl,
                        h16* __restrict__ WhHi, h16* __restrict__ WhLo,
                        h16* __restrict__ WlHi, h16* __restrict__ WlLo) {
  int i = blockIdx.x * 256 + threadIdx.x;          // 262144 elements
  float a = Wh[i];
  h16 h = (h16)a;
  WhHi[i] = h; WhLo[i] = (h16)((a - (float)h) * LO_SCALE);
  a = Wl[i];
  h = (h16)a;
  WlHi[i] = h; WlLo[i] = (h16)((a - (float)h) * LO_SCALE);
}

// ====== gemm9: C[256M x 128N] = A @ B^T (+bias), 8 waves, BK=32 ======
// LDS: dbuf at 0 / 49152, each {A planes [256 rows][hi64|lo64] = 32 KB |
// B planes [128 rows][hi64|lo64] = 16 KB}. Swizzle ^((row&7)<<4) both sides.
// Epilogue repack reuses [0,128K). Static LDS 128 KB -> 1 block/CU.
// AF32=1: A = f32 X, producer-split in-reg (aload 4x f32x4 -> awrite 4x b128).
// AF32=0: A = presplit planes via gload16 (4/thread). B always gload16 (2/thr).
template <int AF32, int EPI>
__launch_bounds__(512, 1)
__global__ void gemm9_k(const void* __restrict__ Aptr, const void* __restrict__ AptrLo,
                        const h16* __restrict__ BHi, const h16* __restrict__ BLo,
                        const float* __restrict__ bias,
                        float* __restrict__ Cf32,
                        h16* __restrict__ OHi, h16* __restrict__ OLo) {
  __shared__ __align__(16) char lds[131072];
  const int tid = threadIdx.x;
  const int wave = tid >> 6, lane = tid & 63;
  const int wm = wave >> 1, wn = wave & 1;         // 4m x 2n waves, 64x64 each
  const int wg = (blockIdx.x & 7) * 128 + (blockIdx.x >> 3);  // XCD-chunked
  const int bm = wg >> 2, bn = wg & 3;             // 256 M-tiles x 4 N-tiles
  const long arow0 = (long)bm * 256;
  const int brow0 = bn * 128;
  const int q = lane >> 4, rlo = lane & 15;

  f32x4 acc_hh[4][4] = {};
  f32x4 acc_mx[4][4] = {};
  f32x4 areg[2][4];                                // K1 only: 2 in-flight steps

  // --- K1 A-path: row = tid>>1 (2 thr/row), 16 f32 (=16 k) per thread ---
  const int axrow = tid >> 1;
  const int akoff = (tid & 1) * 64;                // byte offset of 16 f32 run? no:
  // thread covers k-halves: (tid&1)=0 -> k 0..15, =1 -> k 16..31 (64 B f32 x ... )
  // f32 row = 128 B; half = 64 B = 4 f32x4. Plane half-row = 32 B (16 f16).
  const int asw = (axrow & 7) << 4;

  auto aload = [&](f32x4 (&ar)[4], int kt) {
    const char* base = (const char*)Aptr + (arow0 + axrow) * 2048 + (long)kt * 128 + akoff;
#pragma unroll
    for (int i = 0; i < 4; ++i) ar[i] = *(const f32x4*)(base + i * 16);
  };
  auto awrite = [&](const f32x4 (&ar)[4], char* buf) {
    h16x8 hv[2], lv[2];
#pragma unroll
    for (int p = 0; p < 4; ++p)
#pragma unroll
      for (int e = 0; e < 4; ++e) {
        float a = ar[p][e];
        h16 h = (h16)a;
        hv[p >> 1][(p & 1) * 4 + e] = h;
        lv[p >> 1][(p & 1) * 4 + e] = (h16)((a - (float)h) * LO_SCALE);
      }
    // hi plane bytes [0,64): this thread's 32 B at (tid&1)*32; lo at +64.
    int jb = (tid & 1) * 32;
#pragma unroll
    for (int p = 0; p < 2; ++p) {
      *(h16x8*)(buf + axrow * 128 + ((jb + p * 16) ^ asw)) = hv[p];
      *(h16x8*)(buf + axrow * 128 + ((jb + p * 16 + 64) ^ asw)) = lv[p];
    }
  };
  auto agld = [&](char* buf, int kt) {             // K2: A planes, 4 gload/thr
#pragma unroll
    for (int pass = 0; pass < 4; ++pass) {
      int p = pass * 8192 + wave * 1024 + lane * 16;
      int row = p >> 7;                            // 0..255
      int gs = ((p >> 4) & 7) ^ (row & 7);
      const char* sp = (gs & 4) ? (const char*)AptrLo : (const char*)Aptr;
      long off = (arow0 + row) * 1024 + (long)kt * 64 + (gs & 3) * 16;
      gload16(sp + off, buf + pass * 8192 + wave * 1024);
    }
  };
  auto bgld = [&](char* buf, int kt) {             // B planes, 2 gload/thr
#pragma unroll
    for (int pass = 0; pass < 2; ++pass) {
      int p = pass * 8192 + wave * 1024 + lane * 16;
      int row = p >> 7;                            // 0..127
      int gs = ((p >> 4) & 7) ^ (row & 7);
      const char* sp = (gs & 4) ? (const char*)BLo : (const char*)BHi;
      long off = (long)(brow0 + row) * 1024 + (long)kt * 64 + (gs & 3) * 16;
      gload16(sp + off, buf + 32768 + pass * 8192 + wave * 1024);
    }
  };

  // ---- prologue: stage steps 0,1; step-2 A in flight (K1) ----
  if (AF32) {
    aload(areg[0], 0);
    aload(areg[1], 1);
    WAITV(4);                                      // A0 landed
    awrite(areg[0], lds);
    bgld(lds, 0);
    WAITV(2);                                      // A1 landed (B0 flies)
    awrite(areg[1], lds + 49152);
    aload(areg[0], 2);                             // {B0·2, A2·4}
    bgld(lds + 49152, 1);                          // {B0·2, A2·4, B1·2} = 8
    WAITL0();
  } else {
    agld(lds, 0); bgld(lds, 0);
    agld(lds + 49152, 1); bgld(lds + 49152, 1);    // {S0·6, S1·6} = 12
  }

#pragma unroll
  for (int t = 0; t < 16; ++t) {
    if (AF32) {
      if (t <= 13) { WAITV(6); } else if (t == 14) { WAITV(2); } else { WAITV(0); }
    } else {
      if (t <= 14) { WAITV(6); } else { WAITV(0); }
    }
    SB();
    __builtin_amdgcn_s_barrier();                  // buf[t&1] fully staged
    SB();

    if (AF32 && t <= 12) aload(areg[(t + 3) & 1], t + 3);  // issue-early

    char* buf = lds + (t & 1) * 49152;
    h16x8 ah[4], al[4], bh[4], bl[4];
#pragma unroll
    for (int i = 0; i < 4; ++i) {
      int row = wm * 64 + i * 16 + rlo;
      int sw = (row & 7) << 4;
      ah[i] = *(const h16x8*)(buf + row * 128 + ((q * 16) ^ sw));
      al[i] = *(const h16x8*)(buf + row * 128 + ((q * 16 + 64) ^ sw));
      int rb = wn * 64 + i * 16 + rlo;
      int swb = (rb & 7) << 4;
      bh[i] = *(const h16x8*)(buf + 32768 + rb * 128 + ((q * 16) ^ swb));
      bl[i] = *(const h16x8*)(buf + 32768 + rb * 128 + ((q * 16 + 64) ^ swb));
    }
    __builtin_amdgcn_s_setprio(1);
#pragma unroll
    for (int i = 0; i < 4; ++i)
#pragma unroll
      for (int j = 0; j < 4; ++j)
        acc_hh[i][j] = __builtin_amdgcn_mfma_f32_16x16x32_f16(ah[i], bh[j], acc_hh[i][j], 0, 0, 0);
#pragma unroll
    for (int i = 0; i < 4; ++i)
#pragma unroll
      for (int j = 0; j < 4; ++j)
        acc_mx[i][j] = __builtin_amdgcn_mfma_f32_16x16x32_f16(ah[i], bl[j], acc_mx[i][j], 0, 0, 0);
#pragma unroll
    for (int i = 0; i < 4; ++i)
#pragma unroll
      for (int j = 0; j < 4; ++j)
        acc_mx[i][j] = __builtin_amdgcn_mfma_f32_16x16x32_f16(al[i], bh[j], acc_mx[i][j], 0, 0, 0);
    __builtin_amdgcn_s_setprio(0);

    WAITL0();                                      // our ds_reads of buf done
    SB();
    __builtin_amdgcn_s_barrier();                  // all waves done with buf
    SB();
    if (AF32) {
      if (t <= 12) {
        WAITV(6);                                  // A(t+2) landed
        awrite(areg[(t + 2) & 1], lds + (t & 1) * 49152);
        bgld(lds + (t & 1) * 49152, t + 2);
      } else if (t == 13) {
        WAITV(2);                                  // A15 landed (B14 flies)
        awrite(areg[1], lds + 49152);
        bgld(lds + 49152, 15);
      }
    } else {
      if (t + 2 < 16) { agld(lds + (t & 1) * 49152, t + 2); bgld(lds + (t & 1) * 49152, t + 2); }
    }
  }

  // ---- epilogue: repack [256][128] via LDS, coalesced 16B/lane stores ----
#pragma unroll
  for (int j = 0; j < 4; ++j) {
    int lcol = wn * 64 + j * 16 + rlo;
    float bv = bias[bn * 128 + lcol];
#pragma unroll
    for (int i = 0; i < 4; ++i)
#pragma unroll
      for (int r = 0; r < 4; ++r) {
        int lrow = wm * 64 + i * 16 + q * 4 + r;
        float v = acc_hh[i][j][r] + acc_mx[i][j][r] * LO_INV + bv;
        if (EPI == 0) {
          v = fmaxf(v, 0.0f);
          h16 h = (h16)v;
          h16 l = (h16)((v - (float)h) * LO_SCALE);
          unsigned uu = (unsigned)__builtin_bit_cast(unsigned short, h) |
                        ((unsigned)__builtin_bit_cast(unsigned short, l) << 16);
          *(unsigned*)(lds + lrow * 512 + lcol * 4) = uu;
        } else {
          *(float*)(lds + lrow * 512 + lcol * 4) = v;
        }
      }
  }
  __syncthreads();
#pragma unroll
  for (int pass = 0; pass < 16; ++pass) {
    int o = pass * 8192 + tid * 16;
    int lrow = o >> 9;                             // 512-B packed rows (0..255)
    int lcb = o & 511;
    if (EPI == 0) {
      uint4 d = *(const uint4*)(lds + o);
      uint2 hi, lo;
      hi.x = (d.x & 0xffffu) | (d.y << 16);
      hi.y = (d.z & 0xffffu) | (d.w << 16);
      lo.x = (d.x >> 16) | (d.y & 0xffff0000u);
      lo.y = (d.z >> 16) | (d.w & 0xffff0000u);
      long gb = (arow0 + lrow) * 1024 + bn * 256 + (lcb >> 1);
      *(uint2*)((char*)OHi + gb) = hi;
      *(uint2*)((char*)OLo + gb) = lo;
    } else {
      f32x4 d = *(const f32x4*)(lds + o);
      long gb = (arow0 + lrow) * 2048 + bn * 512 + lcb;
      *(f32x4*)((char*)Cf32 + gb) = d;
    }
  }
}

// ---------------- K3: gumbel + argmax + codebook gather ----------------
__global__ void k3_argmax_gather(const float* __restrict__ logits,
                                 const float* __restrict__ u,
                                 const float* __restrict__ cb,
                                 const int* __restrict__ testing,
                                 float* __restrict__ codes) {
  const int wave = threadIdx.x >> 6, lane = threadIdx.x & 63;
  const long row = (long)blockIdx.x * 4 + wave;    // one wave per row
  const f32x4* lrow = (const f32x4*)(logits + row * 512);
  const f32x4* urow = (const f32x4*)(u + row * 512);
  const int test = *testing;

  float best = -3.4e38f;
  int bi = 0;
#pragma unroll
  for (int h = 0; h < 2; ++h) {
    int c4 = h * 64 + lane;
    f32x4 z = lrow[c4];
    if (!test) {
      f32x4 uu = urow[c4];
#pragma unroll
      for (int t = 0; t < 4; ++t)
        z[t] += -logf(-logf(uu[t] + 1e-20f) + 1e-20f);
    }
#pragma unroll
    for (int t = 0; t < 4; ++t) {                  // in-lane ascending indices
      int c = c4 * 4 + t;
      if (z[t] > best) { best = z[t]; bi = c; }
    }
  }
#pragma unroll
  for (int off = 32; off; off >>= 1) {             // max with min-index ties
    float ob = __shfl_xor(best, off);
    int oi = __shfl_xor(bi, off);
    if (ob > best || (ob == best && oi < bi)) { best = ob; bi = oi; }
  }
  const f32x4* src = (const f32x4*)(cb + (long)bi * 512);
  f32x4* dst = (f32x4*)(codes + row * 512);
  dst[lane] = src[lane];
  dst[lane + 64] = src[lane + 64];
}

// ---------------- host ----------------
extern "C" void kernel_launch(void* const* d_in, const int* in_sizes, int n_in,
                              void* d_out, int out_size, void* d_ws, size_t ws_size,
                              hipStream_t stream) {
  const float* X = (const float*)d_in[0];
  const float* Wh = (const float*)d_in[1];
  const float* bh = (const float*)d_in[2];
  const float* Wl = (const float*)d_in[3];
  const float* bl = (const float*)d_in[4];
  const float* cb = (const float*)d_in[5];
  const float* u = (const float*)d_in[6];
  const int* testing = (const int*)d_in[7];

  float* logits = (float*)d_out;                   // 33554432 f32
  float* codes = logits + 33554432;                // 33554432 f32
  // hiddens hi/lo f16 planes live in the codes region until K3 overwrites it
  h16* Hhi = (h16*)codes;
  h16* Hlo = Hhi + 33554432;

  h16* WhHi = (h16*)d_ws;                          // 4 x 0.5 MB weight planes
  h16* WhLo = WhHi + 262144;
  h16* WlHi = WhLo + 262144;
  h16* WlLo = WlHi + 262144;

  split_w<<<dim3(1024), dim3(256), 0, stream>>>(Wh, Wl, WhHi, WhLo, WlHi, WlLo);

  gemm9_k<1, 0><<<dim3(1024), dim3(512), 0, stream>>>(
      (const void*)X, nullptr, WhHi, WhLo, bh, nullptr, Hhi, Hlo);

  gemm9_k<0, 1><<<dim3(1024), dim3(512), 0, stream>>>(
      (const void*)Hhi, (const void*)Hlo, WlHi, WlLo, bl, logits, nullptr, nullptr);

  k3_argmax_gather<<<dim3(16384), dim3(256), 0, stream>>>(logits, u, cb, testing, codes);
}